// Round 19
// baseline (279.178 us; speedup 1.0000x reference)
//
#include <hip/hip_runtime.h>
#include <hip/hip_bf16.h>

// Attention with softmax over the QUERY axis (axis=1):
//   attn[:,q,k] = exp(S[q,k]) / Z[k],  Z[k] = sum_q exp(S[q,k])
//   out = expS @ (diag(1/Z) V)   -- 1/Z folded into V by k_zv's epilogue.
// B=2, N=8192, D=256. All matmuls via mfma_f32_16x16x32_bf16.
// R19: k_zv rebuilt for occupancy: 256-thr blocks (4 waves), Q-tile 64 rows,
// dbuf 2x32KB -> ~66KB LDS -> 2 blocks/CU, so per-iteration barrier slack
// of one block overlaps the other block's compute. Same read-reuse ratio,
// same staging discipline. k_attn frozen at proven R15/R18 (161us).

#define N_ 8192
#define SCALE 0.0625f

typedef __attribute__((ext_vector_type(8))) short short8;
typedef __attribute__((ext_vector_type(4))) float f32x4;
typedef __attribute__((ext_vector_type(4))) unsigned short ushort4_t;

__device__ inline unsigned short f2bf(float f) {
    unsigned int x = __float_as_uint(f);
    unsigned int r = (x + 0x7fffu + ((x >> 16) & 1u)) >> 16;  // RNE
    return (unsigned short)r;
}

__device__ inline short8 ldg8(const unsigned short* p) {
    return *reinterpret_cast<const short8*>(p);
}

__device__ inline short8 cvt8(const float* p) {
    float4 a = *(const float4*)p;
    float4 b = *(const float4*)(p + 4);
    short8 r;
    r[0] = (short)f2bf(a.x); r[1] = (short)f2bf(a.y);
    r[2] = (short)f2bf(a.z); r[3] = (short)f2bf(a.w);
    r[4] = (short)f2bf(b.x); r[5] = (short)f2bf(b.y);
    r[6] = (short)f2bf(b.z); r[7] = (short)f2bf(b.w);
    return r;
}

__device__ inline f32x4 mfma16(short8 a, short8 b, f32x4 c) {
    return __builtin_amdgcn_mfma_f32_16x16x32_bf16(a, b, c, 0, 0, 0);
}

__device__ inline float bf2f(unsigned short u) {
    return __uint_as_float(((unsigned)u) << 16);
}

#define PIN8(v) asm volatile("" : "+v"(v))

typedef __attribute__((address_space(3))) unsigned int lds_u32;
typedef __attribute__((address_space(1))) const unsigned int glb_u32;
__device__ __forceinline__ void gll16(const void* g, void* l) {
    __builtin_amdgcn_global_load_lds((glb_u32*)g, (lds_u32*)l, 16, 0, 0);
}
#define WAIT_VM0()   asm volatile("s_waitcnt vmcnt(0)" ::: "memory")
#define WAIT_LGKM0() asm volatile("s_waitcnt lgkmcnt(0)" ::: "memory")
#define BARRIER()    __builtin_amdgcn_s_barrier()

// ---------------------------------------------------------------------------
// Kernel 0: W (3 x 256x256 f32) -> Wb (768x256 bf16), concatenated Q|K|V.
// ---------------------------------------------------------------------------
__global__ __launch_bounds__(256) void k_cvtw(
    const float* __restrict__ Wq, const float* __restrict__ Wk,
    const float* __restrict__ Wv, unsigned short* __restrict__ Wb)
{
    int t = blockIdx.x * 256 + threadIdx.x;
    int e8 = t * 8;
    const float* src = (e8 < 65536) ? Wq + e8
                     : (e8 < 131072) ? Wk + (e8 - 65536)
                                     : Wv + (e8 - 131072);
    *reinterpret_cast<short8*>(Wb + e8) = cvt8(src);
}

// ---------------------------------------------------------------------------
// Kernel 1 (v3): QKV projection (proven R14).
// ---------------------------------------------------------------------------
__global__ __launch_bounds__(512, 1) void k_proj(
    const float* __restrict__ x, const unsigned short* __restrict__ Wb,
    unsigned short* __restrict__ Qb, unsigned short* __restrict__ Kb,
    unsigned short* __restrict__ Vt)
{
    extern __shared__ char smem[];
    unsigned short* sX = (unsigned short*)smem;        // 32 KB
    char* sW = smem + 32768;                           // 2 x 32 KB
    const int rb = blockIdx.x;
    const int tid = threadIdx.x, w = tid >> 6, lane = tid & 63;
    const int lr = lane & 15, lg = lane >> 4;
    const int wqs = w >> 2, wes = w & 3;

    int eoff[4], doff[4];
#pragma unroll
    for (int i = 0; i < 4; ++i) {
        int L = tid + i * 512;
        int r = L >> 5, c = (L & 31) ^ (r & 7);
        eoff[i] = r * 256 + c * 8;
        doff[i] = L * 16;
    }

    const unsigned short* wsrc = Wb;
#pragma unroll
    for (int i = 0; i < 4; ++i)
        gll16(wsrc + eoff[i], sW + doff[i]);

#pragma unroll
    for (int i = 0; i < 4; ++i) {
        int g = tid + i * 512;
        int r = g >> 5, c = g & 31;
        int off = (r * 512 + c * 16) ^ ((r & 7) << 4);
        *reinterpret_cast<short8*>(reinterpret_cast<char*>(sX) + off) =
            cvt8(x + (size_t)(rb * 64 + r) * 256 + c * 8);
    }
    __syncthreads();

    short8 xf[2][8];
#pragma unroll
    for (int qf = 0; qf < 2; ++qf)
#pragma unroll
        for (int ks = 0; ks < 8; ++ks) {
            int row = wqs * 32 + qf * 16 + lr;
            int off = (row * 512 + (ks * 32 + lg * 8) * 2) ^ ((row & 7) << 4);
            xf[qf][ks] = *reinterpret_cast<const short8*>(
                reinterpret_cast<const char*>(sX) + off);
            PIN8(xf[qf][ks]);
        }

    for (int c = 0; c < 12; ++c) {
        const int cur = c & 1;
        const char* sWc = sW + cur * 32768;

        WAIT_VM0();
        BARRIER();
        __builtin_amdgcn_sched_barrier(0);

        if (c + 1 < 12) {
            const unsigned short* wn = Wb + (size_t)(c + 1) * 64 * 256;
            char* nW = sW + (cur ^ 1) * 32768;
#pragma unroll
            for (int i = 0; i < 4; ++i)
                gll16(wn + eoff[i], nW + doff[i]);
        }

        f32x4 acc[2] = {};
#pragma unroll
        for (int ks = 0; ks < 8; ++ks) {
            int row = wes * 16 + lr;
            int off = (row * 512 + (ks * 32 + lg * 8) * 2) ^ ((row & 7) << 4);
            short8 wf = *reinterpret_cast<const short8*>(sWc + off);
            acc[0] = mfma16(xf[0][ks], wf, acc[0]);
            acc[1] = mfma16(xf[1][ks], wf, acc[1]);
        }

        int mat = c >> 2;
        int ecol = (c & 3) * 64 + wes * 16 + lr;
#pragma unroll
        for (int qf = 0; qf < 2; ++qf) {
            int rbase = rb * 64 + wqs * 32 + qf * 16 + lg * 4;
            if (mat < 2) {
                unsigned short* dst = (mat == 0) ? Qb : Kb;
#pragma unroll
                for (int r = 0; r < 4; ++r)
                    dst[(size_t)(rbase + r) * 256 + ecol] = f2bf(acc[qf][r]);
            } else {
                int bidx = rbase >> 13, nr = rbase & 8191;
                ushort4_t v;
#pragma unroll
                for (int r = 0; r < 4; ++r) v[r] = f2bf(acc[qf][r]);
                *reinterpret_cast<ushort4_t*>(
                    Vt + ((size_t)bidx * 256 + ecol) * 8192 + nr) = v;
            }
        }
    }
}

// ---------------------------------------------------------------------------
// Kernel 2 (k_zv v2): per (kt,b): Z[k] = sum_q exp(S[q,k]*SCALE), then
// Vt[b][:, kt*64..+64] *= 1/Z in place.
// 256 thr (4 waves: qs=w&1 strip of 32q, kh=w>>1 k-half of 32k).
// Q-tile 64 rows, dbuf 2x32KB (~66KB LDS total) -> 2 blocks/CU.
// 128 iterations; same staging/wait discipline as proven.
// ---------------------------------------------------------------------------
__global__ __launch_bounds__(256, 1) void k_zv(
    const unsigned short* __restrict__ Qb, const unsigned short* __restrict__ Kb,
    unsigned short* __restrict__ Vt)
{
    extern __shared__ char smem[];            // Q dbuf: 2 x 32768 B
    __shared__ float zred[4][32];
    __shared__ float zfin[64];
    const int kt = blockIdx.x, b = blockIdx.y;
    const int tid = threadIdx.x, w = tid >> 6, lane = tid & 63;
    const int lr = lane & 15, lg = lane >> 4;
    const int qs = w & 1, kh = w >> 1;

    // K half-tile in registers: rows kt*64 + kh*32 + kn*16 + lr (64 VGPR)
    short8 kfr[2][8];
#pragma unroll
    for (int kn = 0; kn < 2; ++kn)
#pragma unroll
        for (int ks = 0; ks < 8; ++ks) {
            kfr[kn][ks] = ldg8(
                Kb + (size_t)(b * N_ + kt * 64 + kh * 32 + kn * 16 + lr) * 256
                   + ks * 32 + lg * 8);
            PIN8(kfr[kn][ks]);
        }

    // staging offsets: 2048 granules of 16B per 64q tile; 8 ops/thread
    int eoff[8], doff[8];
#pragma unroll
    for (int i = 0; i < 8; ++i) {
        int L = i * 256 + tid;
        int r = L >> 5, c = (L & 31) ^ (r & 7);
        eoff[i] = r * 256 + c * 8;
        doff[i] = L * 16;
    }
    const unsigned short* qbase = Qb + (size_t)b * N_ * 256;

    // prologue: stage q-tile 0 -> buffer 0
#pragma unroll
    for (int i = 0; i < 8; ++i)
        gll16(qbase + eoff[i], smem + doff[i]);

    float zs0 = 0.f, zs1 = 0.f;
    for (int it = 0; it < 128; ++it) {
        const int cur = it & 1;
        const char* sQ = smem + cur * 32768;

        WAIT_VM0();
        BARRIER();
        __builtin_amdgcn_sched_barrier(0);

        if (it + 1 < 128) {
            const unsigned short* qsrc = qbase + (size_t)(it + 1) * 64 * 256;
            char* nQ = smem + (cur ^ 1) * 32768;
#pragma unroll
            for (int i = 0; i < 8; ++i)
                gll16(qsrc + eoff[i], nQ + doff[i]);
        }

        f32x4 acc[2][2] = {};   // [qf][kn]
        __builtin_amdgcn_s_setprio(1);
#pragma unroll
        for (int ks = 0; ks < 8; ++ks) {
            int coff = (ks * 32 + lg * 8) * 2;
#pragma unroll
            for (int qf = 0; qf < 2; ++qf) {
                int row = qs * 32 + qf * 16 + lr;
                int off = (row * 512 + coff) ^ ((row & 7) << 4);
                short8 qa = *reinterpret_cast<const short8*>(sQ + off);
                acc[qf][0] = mfma16(qa, kfr[0][ks], acc[qf][0]);
                acc[qf][1] = mfma16(qa, kfr[1][ks], acc[qf][1]);
            }
        }
        __builtin_amdgcn_s_setprio(0);

#pragma unroll
        for (int qf = 0; qf < 2; ++qf)
#pragma unroll
            for (int r = 0; r < 4; ++r) {
                zs0 += __expf(acc[qf][0][r] * SCALE);
                zs1 += __expf(acc[qf][1][r] * SCALE);
            }
    }

    // reduce over lane groups (different q, same k)
    zs0 += __shfl_xor(zs0, 16); zs0 += __shfl_xor(zs0, 32);
    zs1 += __shfl_xor(zs1, 16); zs1 += __shfl_xor(zs1, 32);
    if (lg == 0) {
        zred[w][lr]      = zs0;   // k = kh*32 + lr
        zred[w][16 + lr] = zs1;   // k = kh*32 + 16 + lr
    }
    __syncthreads();
    if (tid < 64) {
        int kh2 = tid >> 5, kc = tid & 31;
        float z = zred[kh2 * 2 + 0][kc] + zred[kh2 * 2 + 1][kc];
        zfin[tid] = 1.0f / z;
    }
    __syncthreads();

    // scale Vt[b][d][kt*64 .. +64] in place: 2048 granules of 8 bf16
#pragma unroll
    for (int i = 0; i < 8; ++i) {
        int G = i * 256 + tid;
        int d = G >> 3, c = G & 7;
        unsigned short* p =
            Vt + ((size_t)b * 256 + d) * 8192 + kt * 64 + c * 8;
        short8 v = *reinterpret_cast<short8*>(p);
        short8 o;
#pragma unroll
        for (int j = 0; j < 8; ++j)
            o[j] = (short)f2bf(bf2f((unsigned short)v[j]) * zfin[c * 8 + j]);
        *reinterpret_cast<short8*>(p) = o;
    }
}

// ---------------------------------------------------------------------------
// Kernel 3 (v15): out[q,d] = sum_k exp(S[q,k]*SCALE) * V'[k,d].
// Proven R15/R18 (161us): grid (64 qt, NKH, 2 b), 512 thr, qtile 128, BK 64.
// Waves: wqs=w>>1 (4 strips of 32q); wkh=w&1 (S k-half); wds=w&1 (PV d-half).
// LDS: K dbuf 2x32K @0, V dbuf 2x32K @65536, P 16K @131072 = 144 KB.
// ---------------------------------------------------------------------------
__global__ __launch_bounds__(512, 1) void k_attn(
    const unsigned short* __restrict__ Qb, const unsigned short* __restrict__ Kb,
    const unsigned short* __restrict__ Vt, float* __restrict__ out,
    float* __restrict__ part, int nkt)
{
    extern __shared__ char smem[];
    const int qt = blockIdx.x, kh = blockIdx.y, b = blockIdx.z;
    const int tid = threadIdx.x, w = tid >> 6, lane = tid & 63;
    const int lr = lane & 15, lg = lane >> 4;
    const int qbase = qt * 128;
    const int wqs = w >> 1;          // q strip (32 q)
    const int wkh = w & 1;           // S k-half (32 k)
    const int wds = w & 1;           // PV d-half (128 d)
    const int q0 = wqs * 32;
    const int k0 = kh * nkt * 64;

    const unsigned short* srcK[4];
    const unsigned short* srcV[4];
#pragma unroll
    for (int i = 0; i < 4; ++i) {
        int L = w * 256 + i * 64 + lane;
        int r = L >> 5, c = (L & 31) ^ (r & 7);
        srcK[i] = Kb + (size_t)(b * N_ + k0 + r) * 256 + c * 8;
        int d = L >> 3, c2 = (L & 7) ^ (d & 7);
        srcV[i] = Vt + ((size_t)b * 256 + d) * 8192 + k0 + c2 * 8;
    }

    // prologue: stage tile 0 into buffer 0 (async)
#pragma unroll
    for (int i = 0; i < 4; ++i) {
        gll16(srcK[i], smem + (size_t)(w * 256 + i * 64) * 16);
        gll16(srcV[i], smem + 65536 + (size_t)(w * 256 + i * 64) * 16);
        srcK[i] += 64 * 256;
        srcV[i] += 64;
    }

    // hoist Q fragments: 32 rows (2 frags) x 8 d-slices, PINNED (64 VGPR)
    short8 qfr[2][8];
#pragma unroll
    for (int qf = 0; qf < 2; ++qf) {
        const unsigned short* qrow =
            Qb + (size_t)(b * N_ + qbase + q0 + qf * 16 + lr) * 256;
#pragma unroll
        for (int ks = 0; ks < 8; ++ks) {
            qfr[qf][ks] = ldg8(qrow + ks * 32 + lg * 8);
            PIN8(qfr[qf][ks]);
        }
    }

    f32x4 acco[2][8] = {};

    for (int kt = 0; kt < nkt; ++kt) {
        const int cur = kt & 1;
        char* sK = smem + cur * 32768;
        char* sV = smem + 65536 + cur * 32768;
        char* sP = smem + 131072;

        WAIT_VM0();                  // this wave's staging of tile kt done
        BARRIER();                   // all waves' slices done
        __builtin_amdgcn_sched_barrier(0);

        if (kt + 1 < nkt) {
            char* nK = smem + (cur ^ 1) * 32768;
            char* nV = smem + 65536 + (cur ^ 1) * 32768;
#pragma unroll
            for (int i = 0; i < 4; ++i) {
                gll16(srcK[i], nK + (size_t)(w * 256 + i * 64) * 16);
                gll16(srcV[i], nV + (size_t)(w * 256 + i * 64) * 16);
                srcK[i] += 64 * 256;
                srcV[i] += 64;
            }
        }

        // ---- S phase: 32q x 32k (own k-half) ----
        f32x4 sacc[2][2] = {};       // [qf][kf]
        __builtin_amdgcn_s_setprio(1);
#pragma unroll
        for (int ks = 0; ks < 8; ++ks) {
            int coff = (ks * 32 + lg * 8) * 2;
#pragma unroll
            for (int kf = 0; kf < 2; ++kf) {
                int krow = wkh * 32 + kf * 16 + lr;
                int off = (krow * 512 + coff) ^ ((krow & 7) << 4);
                short8 kb = *reinterpret_cast<const short8*>(sK + off);
                sacc[0][kf] = mfma16(qfr[0][ks], kb, sacc[0][kf]);
                sacc[1][kf] = mfma16(qfr[1][ks], kb, sacc[1][kf]);
            }
        }
        __builtin_amdgcn_s_setprio(0);

        // ---- P = exp(S*SCALE) -> LDS bf16 (swizzled) ----
#pragma unroll
        for (int qf = 0; qf < 2; ++qf)
#pragma unroll
            for (int kf = 0; kf < 2; ++kf)
#pragma unroll
                for (int r = 0; r < 4; ++r) {
                    float p = __expf(sacc[qf][kf][r] * SCALE);
                    int q = q0 + qf * 16 + lg * 4 + r;
                    int kcol = wkh * 32 + kf * 16 + lr;
                    int off = (q * 128 + kcol * 2) ^ ((q & 7) << 4);
                    *reinterpret_cast<unsigned short*>(sP + off) = f2bf(p);
                }

        WAIT_LGKM0();                // P writes drained
        BARRIER();
        __builtin_amdgcn_sched_barrier(0);

        // ---- PV phase: 32q x 128d (own d-half) over 64 k ----
        __builtin_amdgcn_s_setprio(1);
#pragma unroll
        for (int kk = 0; kk < 2; ++kk) {
            int coff = (kk * 32 + lg * 8) * 2;
            short8 pa[2];
#pragma unroll
            for (int qf = 0; qf < 2; ++qf) {
                int qq = q0 + qf * 16 + lr;
                int offa = (qq * 128 + coff) ^ ((qq & 7) << 4);
                pa[qf] = *reinterpret_cast<const short8*>(sP + offa);
            }
#pragma unroll
            for (int df = 0; df < 8; ++df) {
                int d = wds * 128 + df * 16 + lr;
                int offb = (d * 128 + coff) ^ ((d & 7) << 4);
                short8 vb = *reinterpret_cast<const short8*>(sV + offb);
                acco[0][df] = mfma16(pa[0], vb, acco[0][df]);
                acco[1][df] = mfma16(pa[1], vb, acco[1][df]);
            }
        }
        __builtin_amdgcn_s_setprio(0);
    }

    // epilogue: f32 store to out (kh=0) or partial buffer (kh=1)
    float* dst = (kh == 0) ? out : part;
#pragma unroll
    for (int qf = 0; qf < 2; ++qf)
#pragma unroll
        for (int df = 0; df < 8; ++df) {
            int d = wds * 128 + df * 16 + lr;
            int q0r = qbase + q0 + qf * 16 + lg * 4;
#pragma unroll
            for (int r = 0; r < 4; ++r)
                dst[(size_t)(b * N_ + q0r + r) * 256 + d] = acco[qf][df][r];
        }
}

// out += part  (4.2M f32)
__global__ __launch_bounds__(256) void k_add(
    float* __restrict__ out, const float* __restrict__ part)
{
    int t = blockIdx.x * 256 + threadIdx.x;
#pragma unroll
    for (int i = 0; i < 4; ++i) {
        int idx = t + i * 262144;
        float4 a = reinterpret_cast<float4*>(out)[idx];
        float4 p = reinterpret_cast<const float4*>(part)[idx];
        a.x += p.x; a.y += p.y; a.z += p.z; a.w += p.w;
        reinterpret_cast<float4*>(out)[idx] = a;
    }
}

extern "C" void kernel_launch(void* const* d_in, const int* in_sizes, int n_in,
                              void* d_out, int out_size, void* d_ws, size_t ws_size,
                              hipStream_t stream)
{
    const float* x  = (const float*)d_in[0];
    const float* Wq = (const float*)d_in[1];
    const float* Wk = (const float*)d_in[2];
    const float* Wv = (const float*)d_in[3];

    char* ws = (char*)d_ws;
    unsigned short* Qb = (unsigned short*)(ws);              //  8 MB
    unsigned short* Kb = (unsigned short*)(ws + 8388608);    //  8 MB
    unsigned short* Vt = (unsigned short*)(ws + 16777216);   //  8 MB
    unsigned short* Wb = (unsigned short*)(ws + 25165824);   // 384 KB
    float* part1       = (float*)(ws + 25559040);            //  16 MB
    float* out = (float*)d_out;

    k_cvtw<<<dim3(96), dim3(256), 0, stream>>>(Wq, Wk, Wv, Wb);

    hipFuncSetAttribute((const void*)k_proj,
                        hipFuncAttributeMaxDynamicSharedMemorySize, 98304);
    k_proj<<<dim3(256), dim3(512), 98304, stream>>>(x, Wb, Qb, Kb, Vt);

    hipFuncSetAttribute((const void*)k_zv,
                        hipFuncAttributeMaxDynamicSharedMemorySize, 65536);
    k_zv<<<dim3(128, 2), dim3(256), 65536, stream>>>(Qb, Kb, Vt);

    hipFuncSetAttribute((const void*)k_attn,
                        hipFuncAttributeMaxDynamicSharedMemorySize, 147456);
    if (ws_size >= (size_t)25559040 + 16777216) {
        k_attn<<<dim3(64, 2, 2), dim3(512), 147456, stream>>>(
            Qb, Kb, Vt, out, part1, 64);
        k_add<<<dim3(1024), dim3(256), 0, stream>>>(out, part1);
    } else {
        k_attn<<<dim3(64, 1, 2), dim3(512), 147456, stream>>>(
            Qb, Kb, Vt, out, out, 128);
    }
}

// Round 20
// 251.411 us; speedup vs baseline: 1.1104x; 1.1104x over previous
//
#include <hip/hip_runtime.h>
#include <hip/hip_bf16.h>

// Attention with softmax over the QUERY axis (axis=1):
//   attn[:,q,k] = exp(S[q,k]) / Z[k],  Z[k] = sum_q exp(S[q,k])
//   out = expS @ (diag(1/Z) V)   -- 1/Z folded into V by k_zv's epilogue.
// B=2, N=8192, D=256. All matmuls via mfma_f32_16x16x32_bf16.
// R20: revert k_zv to the proven R18 512-thread version. R19's 256-thr k_zv
// kept grid=256 blocks (1/CU) -> 4 waves/CU, HALF the occupancy (the 2/CU
// plan needed 512 blocks, which doubles per-CU Q staging traffic - net loss).
// Banking the best-known 251.7us configuration.

#define N_ 8192
#define SCALE 0.0625f

typedef __attribute__((ext_vector_type(8))) short short8;
typedef __attribute__((ext_vector_type(4))) float f32x4;
typedef __attribute__((ext_vector_type(4))) unsigned short ushort4_t;

__device__ inline unsigned short f2bf(float f) {
    unsigned int x = __float_as_uint(f);
    unsigned int r = (x + 0x7fffu + ((x >> 16) & 1u)) >> 16;  // RNE
    return (unsigned short)r;
}

__device__ inline short8 ldg8(const unsigned short* p) {
    return *reinterpret_cast<const short8*>(p);
}

__device__ inline short8 cvt8(const float* p) {
    float4 a = *(const float4*)p;
    float4 b = *(const float4*)(p + 4);
    short8 r;
    r[0] = (short)f2bf(a.x); r[1] = (short)f2bf(a.y);
    r[2] = (short)f2bf(a.z); r[3] = (short)f2bf(a.w);
    r[4] = (short)f2bf(b.x); r[5] = (short)f2bf(b.y);
    r[6] = (short)f2bf(b.z); r[7] = (short)f2bf(b.w);
    return r;
}

__device__ inline f32x4 mfma16(short8 a, short8 b, f32x4 c) {
    return __builtin_amdgcn_mfma_f32_16x16x32_bf16(a, b, c, 0, 0, 0);
}

__device__ inline float bf2f(unsigned short u) {
    return __uint_as_float(((unsigned)u) << 16);
}

#define PIN8(v) asm volatile("" : "+v"(v))

typedef __attribute__((address_space(3))) unsigned int lds_u32;
typedef __attribute__((address_space(1))) const unsigned int glb_u32;
__device__ __forceinline__ void gll16(const void* g, void* l) {
    __builtin_amdgcn_global_load_lds((glb_u32*)g, (lds_u32*)l, 16, 0, 0);
}
#define WAIT_VM0()   asm volatile("s_waitcnt vmcnt(0)" ::: "memory")
#define WAIT_LGKM0() asm volatile("s_waitcnt lgkmcnt(0)" ::: "memory")
#define BARRIER()    __builtin_amdgcn_s_barrier()

// ---------------------------------------------------------------------------
// Kernel 0: W (3 x 256x256 f32) -> Wb (768x256 bf16), concatenated Q|K|V.
// ---------------------------------------------------------------------------
__global__ __launch_bounds__(256) void k_cvtw(
    const float* __restrict__ Wq, const float* __restrict__ Wk,
    const float* __restrict__ Wv, unsigned short* __restrict__ Wb)
{
    int t = blockIdx.x * 256 + threadIdx.x;
    int e8 = t * 8;
    const float* src = (e8 < 65536) ? Wq + e8
                     : (e8 < 131072) ? Wk + (e8 - 65536)
                                     : Wv + (e8 - 131072);
    *reinterpret_cast<short8*>(Wb + e8) = cvt8(src);
}

// ---------------------------------------------------------------------------
// Kernel 1 (v3): QKV projection (proven R14).
// ---------------------------------------------------------------------------
__global__ __launch_bounds__(512, 1) void k_proj(
    const float* __restrict__ x, const unsigned short* __restrict__ Wb,
    unsigned short* __restrict__ Qb, unsigned short* __restrict__ Kb,
    unsigned short* __restrict__ Vt)
{
    extern __shared__ char smem[];
    unsigned short* sX = (unsigned short*)smem;        // 32 KB
    char* sW = smem + 32768;                           // 2 x 32 KB
    const int rb = blockIdx.x;
    const int tid = threadIdx.x, w = tid >> 6, lane = tid & 63;
    const int lr = lane & 15, lg = lane >> 4;
    const int wqs = w >> 2, wes = w & 3;

    int eoff[4], doff[4];
#pragma unroll
    for (int i = 0; i < 4; ++i) {
        int L = tid + i * 512;
        int r = L >> 5, c = (L & 31) ^ (r & 7);
        eoff[i] = r * 256 + c * 8;
        doff[i] = L * 16;
    }

    const unsigned short* wsrc = Wb;
#pragma unroll
    for (int i = 0; i < 4; ++i)
        gll16(wsrc + eoff[i], sW + doff[i]);

#pragma unroll
    for (int i = 0; i < 4; ++i) {
        int g = tid + i * 512;
        int r = g >> 5, c = g & 31;
        int off = (r * 512 + c * 16) ^ ((r & 7) << 4);
        *reinterpret_cast<short8*>(reinterpret_cast<char*>(sX) + off) =
            cvt8(x + (size_t)(rb * 64 + r) * 256 + c * 8);
    }
    __syncthreads();

    short8 xf[2][8];
#pragma unroll
    for (int qf = 0; qf < 2; ++qf)
#pragma unroll
        for (int ks = 0; ks < 8; ++ks) {
            int row = wqs * 32 + qf * 16 + lr;
            int off = (row * 512 + (ks * 32 + lg * 8) * 2) ^ ((row & 7) << 4);
            xf[qf][ks] = *reinterpret_cast<const short8*>(
                reinterpret_cast<const char*>(sX) + off);
            PIN8(xf[qf][ks]);
        }

    for (int c = 0; c < 12; ++c) {
        const int cur = c & 1;
        const char* sWc = sW + cur * 32768;

        WAIT_VM0();
        BARRIER();
        __builtin_amdgcn_sched_barrier(0);

        if (c + 1 < 12) {
            const unsigned short* wn = Wb + (size_t)(c + 1) * 64 * 256;
            char* nW = sW + (cur ^ 1) * 32768;
#pragma unroll
            for (int i = 0; i < 4; ++i)
                gll16(wn + eoff[i], nW + doff[i]);
        }

        f32x4 acc[2] = {};
#pragma unroll
        for (int ks = 0; ks < 8; ++ks) {
            int row = wes * 16 + lr;
            int off = (row * 512 + (ks * 32 + lg * 8) * 2) ^ ((row & 7) << 4);
            short8 wf = *reinterpret_cast<const short8*>(sWc + off);
            acc[0] = mfma16(xf[0][ks], wf, acc[0]);
            acc[1] = mfma16(xf[1][ks], wf, acc[1]);
        }

        int mat = c >> 2;
        int ecol = (c & 3) * 64 + wes * 16 + lr;
#pragma unroll
        for (int qf = 0; qf < 2; ++qf) {
            int rbase = rb * 64 + wqs * 32 + qf * 16 + lg * 4;
            if (mat < 2) {
                unsigned short* dst = (mat == 0) ? Qb : Kb;
#pragma unroll
                for (int r = 0; r < 4; ++r)
                    dst[(size_t)(rbase + r) * 256 + ecol] = f2bf(acc[qf][r]);
            } else {
                int bidx = rbase >> 13, nr = rbase & 8191;
                ushort4_t v;
#pragma unroll
                for (int r = 0; r < 4; ++r) v[r] = f2bf(acc[qf][r]);
                *reinterpret_cast<ushort4_t*>(
                    Vt + ((size_t)bidx * 256 + ecol) * 8192 + nr) = v;
            }
        }
    }
}

// ---------------------------------------------------------------------------
// Kernel 2 (k_zv): per (kt,b): Z[k] = sum_q exp(S[q,k]*SCALE), then
// Vt[b][:, kt*64..+64] *= 1/Z in place. (Proven R10/R18, ~55us.)
// ---------------------------------------------------------------------------
__global__ __launch_bounds__(512, 1) void k_zv(
    const unsigned short* __restrict__ Qb, const unsigned short* __restrict__ Kb,
    unsigned short* __restrict__ Vt)
{
    extern __shared__ char smem[];            // Q dbuf: 2 x 65536 B
    __shared__ float zred[8][32];
    __shared__ float zfin[64];
    const int kt = blockIdx.x, b = blockIdx.y;
    const int tid = threadIdx.x, w = tid >> 6, lane = tid & 63;
    const int lr = lane & 15, lg = lane >> 4;
    const int qs = w & 3, kh = w >> 2;

    short8 kfr[2][8];
#pragma unroll
    for (int kn = 0; kn < 2; ++kn)
#pragma unroll
        for (int ks = 0; ks < 8; ++ks) {
            kfr[kn][ks] = ldg8(
                Kb + (size_t)(b * N_ + kt * 64 + kh * 32 + kn * 16 + lr) * 256
                   + ks * 32 + lg * 8);
            PIN8(kfr[kn][ks]);
        }

    int eoff[8], doff[8];
#pragma unroll
    for (int i = 0; i < 8; ++i) {
        int L = i * 512 + w * 64 + lane;
        int r = L >> 5, c = (L & 31) ^ (r & 7);
        eoff[i] = r * 256 + c * 8;
        doff[i] = L * 16;
    }
    const unsigned short* qbase = Qb + (size_t)b * N_ * 256;

#pragma unroll
    for (int i = 0; i < 8; ++i)
        gll16(qbase + eoff[i], smem + doff[i]);

    float zs0 = 0.f, zs1 = 0.f;
    for (int it = 0; it < 64; ++it) {
        const int cur = it & 1;
        const char* sQ = smem + cur * 65536;

        WAIT_VM0();
        BARRIER();
        __builtin_amdgcn_sched_barrier(0);

        if (it + 1 < 64) {
            const unsigned short* qsrc = qbase + (size_t)(it + 1) * 128 * 256;
            char* nQ = smem + (cur ^ 1) * 65536;
#pragma unroll
            for (int i = 0; i < 8; ++i)
                gll16(qsrc + eoff[i], nQ + doff[i]);
        }

        f32x4 acc[2][2] = {};
        __builtin_amdgcn_s_setprio(1);
#pragma unroll
        for (int ks = 0; ks < 8; ++ks) {
            int coff = (ks * 32 + lg * 8) * 2;
#pragma unroll
            for (int qf = 0; qf < 2; ++qf) {
                int row = qs * 32 + qf * 16 + lr;
                int off = (row * 512 + coff) ^ ((row & 7) << 4);
                short8 qa = *reinterpret_cast<const short8*>(sQ + off);
                acc[qf][0] = mfma16(qa, kfr[0][ks], acc[qf][0]);
                acc[qf][1] = mfma16(qa, kfr[1][ks], acc[qf][1]);
            }
        }
        __builtin_amdgcn_s_setprio(0);

#pragma unroll
        for (int qf = 0; qf < 2; ++qf)
#pragma unroll
            for (int r = 0; r < 4; ++r) {
                zs0 += __expf(acc[qf][0][r] * SCALE);
                zs1 += __expf(acc[qf][1][r] * SCALE);
            }
    }

    zs0 += __shfl_xor(zs0, 16); zs0 += __shfl_xor(zs0, 32);
    zs1 += __shfl_xor(zs1, 16); zs1 += __shfl_xor(zs1, 32);
    if (lg == 0) {
        zred[w][lr]      = zs0;
        zred[w][16 + lr] = zs1;
    }
    __syncthreads();
    if (tid < 64) {
        int kh2 = tid >> 5, kc = tid & 31;
        float z = zred[kh2 * 4 + 0][kc] + zred[kh2 * 4 + 1][kc] +
                  zred[kh2 * 4 + 2][kc] + zred[kh2 * 4 + 3][kc];
        zfin[tid] = 1.0f / z;
    }
    __syncthreads();

#pragma unroll
    for (int i = 0; i < 4; ++i) {
        int G = i * 512 + tid;
        int d = G >> 3, c = G & 7;
        unsigned short* p =
            Vt + ((size_t)b * 256 + d) * 8192 + kt * 64 + c * 8;
        short8 v = *reinterpret_cast<short8*>(p);
        short8 o;
#pragma unroll
        for (int j = 0; j < 8; ++j)
            o[j] = (short)f2bf(bf2f((unsigned short)v[j]) * zfin[c * 8 + j]);
        *reinterpret_cast<short8*>(p) = o;
    }
}

// ---------------------------------------------------------------------------
// Kernel 3 (v15): out[q,d] = sum_k exp(S[q,k]*SCALE) * V'[k,d].
// Proven R15/R18 (161us): grid (64 qt, NKH, 2 b), 512 thr, qtile 128, BK 64.
// Waves: wqs=w>>1 (4 strips of 32q); wkh=w&1 (S k-half); wds=w&1 (PV d-half).
// LDS: K dbuf 2x32K @0, V dbuf 2x32K @65536, P 16K @131072 = 144 KB.
// ---------------------------------------------------------------------------
__global__ __launch_bounds__(512, 1) void k_attn(
    const unsigned short* __restrict__ Qb, const unsigned short* __restrict__ Kb,
    const unsigned short* __restrict__ Vt, float* __restrict__ out,
    float* __restrict__ part, int nkt)
{
    extern __shared__ char smem[];
    const int qt = blockIdx.x, kh = blockIdx.y, b = blockIdx.z;
    const int tid = threadIdx.x, w = tid >> 6, lane = tid & 63;
    const int lr = lane & 15, lg = lane >> 4;
    const int qbase = qt * 128;
    const int wqs = w >> 1;          // q strip (32 q)
    const int wkh = w & 1;           // S k-half (32 k)
    const int wds = w & 1;           // PV d-half (128 d)
    const int q0 = wqs * 32;
    const int k0 = kh * nkt * 64;

    const unsigned short* srcK[4];
    const unsigned short* srcV[4];
#pragma unroll
    for (int i = 0; i < 4; ++i) {
        int L = w * 256 + i * 64 + lane;
        int r = L >> 5, c = (L & 31) ^ (r & 7);
        srcK[i] = Kb + (size_t)(b * N_ + k0 + r) * 256 + c * 8;
        int d = L >> 3, c2 = (L & 7) ^ (d & 7);
        srcV[i] = Vt + ((size_t)b * 256 + d) * 8192 + k0 + c2 * 8;
    }

    // prologue: stage tile 0 into buffer 0 (async)
#pragma unroll
    for (int i = 0; i < 4; ++i) {
        gll16(srcK[i], smem + (size_t)(w * 256 + i * 64) * 16);
        gll16(srcV[i], smem + 65536 + (size_t)(w * 256 + i * 64) * 16);
        srcK[i] += 64 * 256;
        srcV[i] += 64;
    }

    // hoist Q fragments: 32 rows (2 frags) x 8 d-slices, PINNED (64 VGPR)
    short8 qfr[2][8];
#pragma unroll
    for (int qf = 0; qf < 2; ++qf) {
        const unsigned short* qrow =
            Qb + (size_t)(b * N_ + qbase + q0 + qf * 16 + lr) * 256;
#pragma unroll
        for (int ks = 0; ks < 8; ++ks) {
            qfr[qf][ks] = ldg8(qrow + ks * 32 + lg * 8);
            PIN8(qfr[qf][ks]);
        }
    }

    f32x4 acco[2][8] = {};

    for (int kt = 0; kt < nkt; ++kt) {
        const int cur = kt & 1;
        char* sK = smem + cur * 32768;
        char* sV = smem + 65536 + cur * 32768;
        char* sP = smem + 131072;

        WAIT_VM0();                  // this wave's staging of tile kt done
        BARRIER();                   // all waves' slices done
        __builtin_amdgcn_sched_barrier(0);

        if (kt + 1 < nkt) {
            char* nK = smem + (cur ^ 1) * 32768;
            char* nV = smem + 65536 + (cur ^ 1) * 32768;
#pragma unroll
            for (int i = 0; i < 4; ++i) {
                gll16(srcK[i], nK + (size_t)(w * 256 + i * 64) * 16);
                gll16(srcV[i], nV + (size_t)(w * 256 + i * 64) * 16);
                srcK[i] += 64 * 256;
                srcV[i] += 64;
            }
        }

        // ---- S phase: 32q x 32k (own k-half) ----
        f32x4 sacc[2][2] = {};       // [qf][kf]
        __builtin_amdgcn_s_setprio(1);
#pragma unroll
        for (int ks = 0; ks < 8; ++ks) {
            int coff = (ks * 32 + lg * 8) * 2;
#pragma unroll
            for (int kf = 0; kf < 2; ++kf) {
                int krow = wkh * 32 + kf * 16 + lr;
                int off = (krow * 512 + coff) ^ ((krow & 7) << 4);
                short8 kb = *reinterpret_cast<const short8*>(sK + off);
                sacc[0][kf] = mfma16(qfr[0][ks], kb, sacc[0][kf]);
                sacc[1][kf] = mfma16(qfr[1][ks], kb, sacc[1][kf]);
            }
        }
        __builtin_amdgcn_s_setprio(0);

        // ---- P = exp(S*SCALE) -> LDS bf16 (swizzled) ----
#pragma unroll
        for (int qf = 0; qf < 2; ++qf)
#pragma unroll
            for (int kf = 0; kf < 2; ++kf)
#pragma unroll
                for (int r = 0; r < 4; ++r) {
                    float p = __expf(sacc[qf][kf][r] * SCALE);
                    int q = q0 + qf * 16 + lg * 4 + r;
                    int kcol = wkh * 32 + kf * 16 + lr;
                    int off = (q * 128 + kcol * 2) ^ ((q & 7) << 4);
                    *reinterpret_cast<unsigned short*>(sP + off) = f2bf(p);
                }

        WAIT_LGKM0();                // P writes drained
        BARRIER();
        __builtin_amdgcn_sched_barrier(0);

        // ---- PV phase: 32q x 128d (own d-half) over 64 k ----
        __builtin_amdgcn_s_setprio(1);
#pragma unroll
        for (int kk = 0; kk < 2; ++kk) {
            int coff = (kk * 32 + lg * 8) * 2;
            short8 pa[2];
#pragma unroll
            for (int qf = 0; qf < 2; ++qf) {
                int qq = q0 + qf * 16 + lr;
                int offa = (qq * 128 + coff) ^ ((qq & 7) << 4);
                pa[qf] = *reinterpret_cast<const short8*>(sP + offa);
            }
#pragma unroll
            for (int df = 0; df < 8; ++df) {
                int d = wds * 128 + df * 16 + lr;
                int offb = (d * 128 + coff) ^ ((d & 7) << 4);
                short8 vb = *reinterpret_cast<const short8*>(sV + offb);
                acco[0][df] = mfma16(pa[0], vb, acco[0][df]);
                acco[1][df] = mfma16(pa[1], vb, acco[1][df]);
            }
        }
        __builtin_amdgcn_s_setprio(0);
    }

    // epilogue: f32 store to out (kh=0) or partial buffer (kh=1)
    float* dst = (kh == 0) ? out : part;
#pragma unroll
    for (int qf = 0; qf < 2; ++qf)
#pragma unroll
        for (int df = 0; df < 8; ++df) {
            int d = wds * 128 + df * 16 + lr;
            int q0r = qbase + q0 + qf * 16 + lg * 4;
#pragma unroll
            for (int r = 0; r < 4; ++r)
                dst[(size_t)(b * N_ + q0r + r) * 256 + d] = acco[qf][df][r];
        }
}

// out += part  (4.2M f32)
__global__ __launch_bounds__(256) void k_add(
    float* __restrict__ out, const float* __restrict__ part)
{
    int t = blockIdx.x * 256 + threadIdx.x;
#pragma unroll
    for (int i = 0; i < 4; ++i) {
        int idx = t + i * 262144;
        float4 a = reinterpret_cast<float4*>(out)[idx];
        float4 p = reinterpret_cast<const float4*>(part)[idx];
        a.x += p.x; a.y += p.y; a.z += p.z; a.w += p.w;
        reinterpret_cast<float4*>(out)[idx] = a;
    }
}

extern "C" void kernel_launch(void* const* d_in, const int* in_sizes, int n_in,
                              void* d_out, int out_size, void* d_ws, size_t ws_size,
                              hipStream_t stream)
{
    const float* x  = (const float*)d_in[0];
    const float* Wq = (const float*)d_in[1];
    const float* Wk = (const float*)d_in[2];
    const float* Wv = (const float*)d_in[3];

    char* ws = (char*)d_ws;
    unsigned short* Qb = (unsigned short*)(ws);              //  8 MB
    unsigned short* Kb = (unsigned short*)(ws + 8388608);    //  8 MB
    unsigned short* Vt = (unsigned short*)(ws + 16777216);   //  8 MB
    unsigned short* Wb = (unsigned short*)(ws + 25165824);   // 384 KB
    float* part1       = (float*)(ws + 25559040);            //  16 MB
    float* out = (float*)d_out;

    k_cvtw<<<dim3(96), dim3(256), 0, stream>>>(Wq, Wk, Wv, Wb);

    hipFuncSetAttribute((const void*)k_proj,
                        hipFuncAttributeMaxDynamicSharedMemorySize, 98304);
    k_proj<<<dim3(256), dim3(512), 98304, stream>>>(x, Wb, Qb, Kb, Vt);

    hipFuncSetAttribute((const void*)k_zv,
                        hipFuncAttributeMaxDynamicSharedMemorySize, 131072);
    k_zv<<<dim3(128, 2), dim3(512), 131072, stream>>>(Qb, Kb, Vt);

    hipFuncSetAttribute((const void*)k_attn,
                        hipFuncAttributeMaxDynamicSharedMemorySize, 147456);
    if (ws_size >= (size_t)25559040 + 16777216) {
        k_attn<<<dim3(64, 2, 2), dim3(512), 147456, stream>>>(
            Qb, Kb, Vt, out, part1, 64);
        k_add<<<dim3(1024), dim3(256), 0, stream>>>(out, part1);
    } else {
        k_attn<<<dim3(64, 1, 2), dim3(512), 147456, stream>>>(
            Qb, Kb, Vt, out, out, 128);
    }
}